// Round 10
// baseline (502.357 us; speedup 1.0000x reference)
//
#include <hip/hip_runtime.h>
#include <hip/hip_bf16.h>

#define Bn 256
#define Tn 200
#define En 100
#define Hn 128
#define Kn 13
#define G4 512          // 4H
#define BT 51200        // B*T

typedef __attribute__((ext_vector_type(8))) __bf16 bf8_t;
typedef __attribute__((ext_vector_type(8))) unsigned short us8_t;
typedef __attribute__((ext_vector_type(4))) float f4_t;

__device__ __forceinline__ unsigned short f2bf(float f) {
  unsigned int u = __float_as_uint(f);
  u = (u + 0x7FFFu + ((u >> 16) & 1u)) >> 16;
  return (unsigned short)u;
}
__device__ __forceinline__ float bf2f(unsigned short s) {
  return __uint_as_float(((unsigned int)s) << 16);
}
__device__ __forceinline__ float sigm(float x) { return 1.f / (1.f + __expf(-x)); }

// LDS-only barrier: drains lgkmcnt but lets VMEM stay in flight across it.
__device__ __forceinline__ void bar_lgkm() {
  asm volatile("s_waitcnt lgkmcnt(0)" ::: "memory");
  __builtin_amdgcn_s_barrier();
  __builtin_amdgcn_sched_barrier(0);
}

// Gate permutation: permuted col n holds original col g*128 + j with
// g=(n>>4)&3, j=(n>>6)*16+(n&15) -> gates i,f,g,o of unit j land in one
// scan lane's acc0..3.
__device__ __forceinline__ int gperm(int n) {
  return ((n >> 4) & 3) * 128 + ((n >> 6) << 4) + (n & 15);
}

// ---------- lens ----------
__global__ __launch_bounds__(64) void k_lens(const int* __restrict__ text,
                                             int* __restrict__ lens_i,
                                             float* __restrict__ out_lens) {
  int b = blockIdx.x, lane = threadIdx.x;
  int cnt = 0;
  for (int t = lane; t < Tn; t += 64) cnt += (text[b * Tn + t] != 0);
  for (int off = 32; off; off >>= 1) cnt += __shfl_down(cnt, off);
  if (lane == 0) { lens_i[b] = cnt; out_lens[b] = (float)cnt; }
}

// ---------- W,U -> permuted-transposed bf16: wt[2][512][128], ut[2][512][128] ----------
__global__ __launch_bounds__(256) void k_wt(const float* __restrict__ Wf,
                                            const float* __restrict__ Wb,
                                            const float* __restrict__ Uf,
                                            const float* __restrict__ Ub,
                                            unsigned short* __restrict__ wt,
                                            unsigned short* __restrict__ ut) {
  int idx = blockIdx.x * 256 + threadIdx.x;   // 0..262143
  int half = idx >> 17;                        // 0:W  1:U
  int rem = idx & 131071;
  int dir = rem >> 16;
  int nk = rem & 65535;
  int n = nk >> 7, k = nk & 127;
  int mc = gperm(n);
  if (half == 0) {
    const float* W = dir ? Wb : Wf;
    wt[rem] = f2bf((k < En) ? W[k * G4 + mc] : 0.f);
  } else {
    const float* U = dir ? Ub : Uf;
    ut[rem] = f2bf(U[k * G4 + mc]);
  }
}

// ---------- embedding gather -> bf16 padded x[BT][128] ----------
__global__ __launch_bounds__(256) void k_gather(const int* __restrict__ text,
                                                const float* __restrict__ emb,
                                                unsigned short* __restrict__ xg) {
  int row = blockIdx.x * 128 + (threadIdx.x >> 1);
  int half = threadIdx.x & 1;
  int tok = text[row];
  const float* er = emb + (size_t)tok * En;
  unsigned short* xr = xg + (size_t)row * 128 + half * 64;
  #pragma unroll
  for (int c = 0; c < 64; c += 2) {
    int col = half * 64 + c;
    float v0 = (col < En) ? er[col] : 0.f;
    float v1 = (col + 1 < En) ? er[col + 1] : 0.f;
    unsigned int pk = (unsigned int)f2bf(v0) | ((unsigned int)f2bf(v1) << 16);
    *(unsigned int*)(xr + c) = pk;
  }
}

// ---------- xw = x@Wperm + bperm, stored SCAN-NATIVE: [t][bg][tid][e] ----------
// e = q*4+nt; tid = w*64+lg*16+lr; b = bg*16+lg*4+q; col = w*64+nt*16+lr.
// Scan thread then reads its 16 per-step values as ONE contiguous 32B chunk.
__global__ __launch_bounds__(256) void k_gemm_xw(const unsigned short* __restrict__ xg,
                                                 const unsigned short* __restrict__ wt,
                                                 const float* __restrict__ biasf,
                                                 const float* __restrict__ biasb,
                                                 unsigned short* __restrict__ xwf,
                                                 unsigned short* __restrict__ xwb) {
  __shared__ unsigned short As[128 * 128];
  __shared__ unsigned short Bs[128 * 128];
  int mt = blockIdx.x;              // 0..399
  int dir = blockIdx.y >> 2;        // 0=f,1=b
  int nt = blockIdx.y & 3;          // 0..3 (128-wide N tiles)
  const float* bias = dir ? biasb : biasf;
  unsigned short* out = dir ? xwb : xwf;
  int tid = threadIdx.x;
  const unsigned short* wt_d = wt + (size_t)dir * (G4 * 128);

  #pragma unroll
  for (int it = 0; it < 8; it++) {
    int idx = it * 256 + tid;
    int r = idx >> 4, c = idx & 15;
    bf8_t va = *(const bf8_t*)(xg + ((size_t)mt * 128 + r) * 128 + c * 8);
    bf8_t vb = *(const bf8_t*)(wt_d + ((size_t)nt * 128 + r) * 128 + c * 8);
    int byte = (r * 256 + c * 16) ^ ((r & 7) << 4);
    *(bf8_t*)((char*)As + byte) = va;
    *(bf8_t*)((char*)Bs + byte) = vb;
  }
  __syncthreads();
  int wid = tid >> 6, lane = tid & 63;
  int wm = wid >> 1, wn = wid & 1;
  int lr = lane & 15, lk = lane >> 4;
  f4_t zero = {0.f, 0.f, 0.f, 0.f};
  f4_t acc[4][4];
  #pragma unroll
  for (int m = 0; m < 4; m++)
    #pragma unroll
    for (int n = 0; n < 4; n++) acc[m][n] = zero;
  #pragma unroll
  for (int kk = 0; kk < 4; kk++) {
    bf8_t af[4], bv[4];
    #pragma unroll
    for (int m = 0; m < 4; m++) {
      int r = wm * 64 + m * 16 + lr;
      int byte = (r * 256 + kk * 64 + lk * 16) ^ ((r & 7) << 4);
      af[m] = *(const bf8_t*)((const char*)As + byte);
    }
    #pragma unroll
    for (int n = 0; n < 4; n++) {
      int r = wn * 64 + n * 16 + lr;
      int byte = (r * 256 + kk * 64 + lk * 16) ^ ((r & 7) << 4);
      bv[n] = *(const bf8_t*)((const char*)Bs + byte);
    }
    #pragma unroll
    for (int m = 0; m < 4; m++)
      #pragma unroll
      for (int n = 0; n < 4; n++)
        acc[m][n] = __builtin_amdgcn_mfma_f32_16x16x32_bf16(af[m], bv[n], acc[m][n], 0, 0, 0);
  }
  float bn[4];
  int w2[4], nt2[4], lr2[4];
  #pragma unroll
  for (int n = 0; n < 4; n++) {
    int colg = nt * 128 + wn * 64 + n * 16 + lr;
    bn[n] = bias[gperm(colg)];
    w2[n] = colg >> 6; nt2[n] = (colg >> 4) & 3; lr2[n] = colg & 15;
  }
  #pragma unroll
  for (int m = 0; m < 4; m++) {
    int rowl = wm * 64 + m * 16 + lk * 4;
    #pragma unroll
    for (int q = 0; q < 4; q++) {
      int row = mt * 128 + rowl + q;
      int b = row / 200;
      int t = row - b * 200;
      int bg = b >> 4, lg2 = (b >> 2) & 3, qq = b & 3;
      size_t base = (((size_t)t * 16 + bg) * 512) * 16;
      #pragma unroll
      for (int n = 0; n < 4; n++) {
        size_t dst = base + (size_t)(w2[n] * 64 + lg2 * 16 + lr2[n]) * 16 + (qq * 4 + nt2[n]);
        out[dst] = f2bf(acc[m][n][q] + bn[n]);
      }
    }
  }
}

// ---------- recurrent scan, MFMA version (R10) ----------
// R9 post-mortem: step pinned at ~3200cy across 3 structural fixes; pipes
// mostly idle -> wait-dominated. Invariant suspect: 16 scalar u16 prefetch
// loads/thread/step consumed 1 step later. R10: scan-native xw layout ->
// prefetch = 2 x b128 loads (32B contiguous/thread); depth-2 prefetch (2
// named reg sets, 2-step unroll) -> ~2-step window covers L3 latency;
// h global stores moved after the barrier.
#define UB16(M) M(0,0) M(0,1) M(0,2) M(0,3) M(1,0) M(1,1) M(1,2) M(1,3) \
                M(2,0) M(2,1) M(2,2) M(2,3) M(3,0) M(3,1) M(3,2) M(3,3)

__global__ __attribute__((amdgpu_flat_work_group_size(512, 512),
                          amdgpu_waves_per_eu(1, 2)))
void k_scan(const unsigned short* __restrict__ ut,
            const unsigned short* __restrict__ xw2,
            unsigned short* __restrict__ hf,
            unsigned short* __restrict__ hb) {
  int blk = blockIdx.x;              // 0..31
  int dir = blk >> 4;
  int bg = blk & 15;
  int b0 = bg * 16;
  int tid = threadIdx.x;
  int w = tid >> 6, l = tid & 63;
  int lr = l & 15, lg = l >> 4;
  int r0 = lg * 4;
  int jj = w * 16 + lr;
  const unsigned short* ut_d = ut + (size_t)dir * (G4 * 128);
  const unsigned short* xw_d = xw2 + (size_t)dir * ((size_t)BT * G4);
  unsigned short* hout = dir ? hb : hf;
  int t0 = dir ? (Tn - 1) : 0;
  int dt = dir ? -1 : 1;

  // U B-frags pinned into AGPRs: frag(nt,kk) = cols w*64+nt*16+lr, k=kk*32+lg*8..+7
#define LOADUB(nt, kk) \
  bf8_t ub_##nt##_##kk = *(const bf8_t*)(ut_d + (size_t)(w * 64 + (nt) * 16 + lr) * 128 + (kk) * 32 + lg * 8); \
  asm volatile("" : "+a"(ub_##nt##_##kk));
  UB16(LOADUB)
#undef LOADUB

  __shared__ unsigned short h_lds[2][2048];   // two 4KB halves, XOR-swizzled rows
  for (int i = tid; i < 1024; i += 512) ((unsigned int*)h_lds)[i] = 0;

  int rb0 = (lr * 256 +   0 + lg * 16) ^ ((lr & 7) << 4);
  int rb1 = (lr * 256 +  64 + lg * 16) ^ ((lr & 7) << 4);
  int rb2 = (lr * 256 + 128 + lg * 16) ^ ((lr & 7) << 4);
  int rb3 = (lr * 256 + 192 + lg * 16) ^ ((lr & 7) << 4);
  int wb0 = (((r0 + 0) * 256 + jj * 2) ^ (((r0 + 0) & 7) << 4)) + 4096;
  int wb1 = (((r0 + 1) * 256 + jj * 2) ^ (((r0 + 1) & 7) << 4)) + 4096;
  int wb2 = (((r0 + 2) * 256 + jj * 2) ^ (((r0 + 2) & 7) << 4)) + 4096;
  int wb3 = (((r0 + 3) * 256 + jj * 2) ^ (((r0 + 3) & 7) << 4)) + 4096;
  char* lbase = (char*)h_lds;

  const unsigned short* xptr = xw_d + ((size_t)t0 * 16 + bg) * 8192 + tid * 16;
  const long long xstep = (long long)dt * 131072;     // 16*512*16 u16 per t
  unsigned short* hp = hout + ((size_t)t0 * Bn + b0 + r0) * 128 + jj;
  const long long hstep = (long long)dt * Bn * 128;

  // depth-2 prefetch: A=t0, B=t0+dt in flight before the loop
  us8_t xa0 = *(const us8_t*)(xptr);
  us8_t xa1 = *(const us8_t*)(xptr + 8);
  us8_t xb0 = *(const us8_t*)(xptr + xstep);
  us8_t xb1 = *(const us8_t*)(xptr + xstep + 8);
  xptr += 2 * xstep;

  float c0 = 0.f, c1 = 0.f, c2 = 0.f, c3 = 0.f;
  bar_lgkm();

#define MF(nt, kk) acc##nt = __builtin_amdgcn_mfma_f32_16x16x32_bf16(af##kk, ub_##nt##_##kk, acc##nt, 0, 0, 0);
#define GATEQ(q, HS) { \
    float ig = sigm(acc0[q]); \
    float fg = sigm(acc1[q]); \
    float gg = fmaxf(acc2[q], 0.f); \
    c##q = fmaf(fg, c##q, ig * gg); \
    HS = f2bf(sigm(acc3[q]) * fmaxf(c##q, 0.f)); \
    *(unsigned short*)(lbase + wb##q) = HS; }

#define STEP(X0, X1, ISSUE_OK) { \
    f4_t acc0, acc1, acc2, acc3; \
    acc0[0] = bf2f(X0[0]); acc0[1] = bf2f(X0[4]); acc0[2] = bf2f(X1[0]); acc0[3] = bf2f(X1[4]); \
    acc1[0] = bf2f(X0[1]); acc1[1] = bf2f(X0[5]); acc1[2] = bf2f(X1[1]); acc1[3] = bf2f(X1[5]); \
    acc2[0] = bf2f(X0[2]); acc2[1] = bf2f(X0[6]); acc2[2] = bf2f(X1[2]); acc2[3] = bf2f(X1[6]); \
    acc3[0] = bf2f(X0[3]); acc3[1] = bf2f(X0[7]); acc3[2] = bf2f(X1[3]); acc3[3] = bf2f(X1[7]); \
    if (ISSUE_OK) { X0 = *(const us8_t*)(xptr); X1 = *(const us8_t*)(xptr + 8); } \
    xptr += xstep; \
    bf8_t af0 = *(const bf8_t*)(lbase + rb0); \
    bf8_t af1 = *(const bf8_t*)(lbase + rb1); \
    bf8_t af2 = *(const bf8_t*)(lbase + rb2); \
    bf8_t af3 = *(const bf8_t*)(lbase + rb3); \
    MF(0,0) MF(1,0) MF(2,0) MF(3,0) \
    MF(0,1) MF(1,1) MF(2,1) MF(3,1) \
    MF(0,2) MF(1,2) MF(2,2) MF(3,2) \
    MF(0,3) MF(1,3) MF(2,3) MF(3,3) \
    unsigned short h0s, h1s, h2s, h3s; \
    GATEQ(0, h0s) GATEQ(1, h1s) GATEQ(2, h2s) GATEQ(3, h3s) \
    bar_lgkm(); \
    hp[0] = h0s; hp[128] = h1s; hp[256] = h2s; hp[384] = h3s; \
    rb0 ^= 4096; rb1 ^= 4096; rb2 ^= 4096; rb3 ^= 4096; \
    wb0 ^= 4096; wb1 ^= 4096; wb2 ^= 4096; wb3 ^= 4096; \
    hp += hstep; }

  for (int tt = 0; tt < Tn; tt += 2) {
    STEP(xa0, xa1, tt < Tn - 2)
    STEP(xb0, xb1, tt < Tn - 3)
  }
#undef STEP
#undef GATEQ
#undef MF
}

// ---------- logits = softmax([hf|hb] @ Wd + bd); h rows are (t*Bn+b) ----------
__global__ __launch_bounds__(128) void k_logits(const unsigned short* __restrict__ hf,
                                                const unsigned short* __restrict__ hb,
                                                const float* __restrict__ Wd,
                                                const float* __restrict__ bd,
                                                float* __restrict__ out) {
  __shared__ unsigned short hs[128 * 256];   // 64KB, XOR-swizzled rows of 512B
  int tid = threadIdx.x;
  size_t row0 = (size_t)blockIdx.x * 128;
  #pragma unroll
  for (int it = 0; it < 16; it++) {
    int idx = it * 128 + tid;
    int r = idx >> 4, c = idx & 15;
    bf8_t vf = *(const bf8_t*)(hf + (row0 + r) * 128 + c * 8);
    bf8_t vb = *(const bf8_t*)(hb + (row0 + r) * 128 + c * 8);
    int byte = (r * 512 + c * 16) ^ ((r & 7) << 4);
    *(bf8_t*)((char*)hs + byte) = vf;
    int byte2 = (r * 512 + 256 + c * 16) ^ ((r & 7) << 4);
    *(bf8_t*)((char*)hs + byte2) = vb;
  }
  __syncthreads();
  float acc[Kn];
  #pragma unroll
  for (int jj = 0; jj < Kn; jj++) acc[jj] = bd[jj];
  int r = tid;
  #pragma unroll 4
  for (int c = 0; c < 32; c++) {
    int byte = (r * 512 + c * 16) ^ ((r & 7) << 4);
    bf8_t v = *(const bf8_t*)((const char*)hs + byte);
    #pragma unroll
    for (int e = 0; e < 8; e++) {
      float h = (float)v[e];
      int k = c * 8 + e;
      #pragma unroll
      for (int jj = 0; jj < Kn; jj++)
        acc[jj] = fmaf(h, Wd[k * Kn + jj], acc[jj]);   // uniform -> scalar loads
    }
  }
  float m = acc[0];
  #pragma unroll
  for (int jj = 1; jj < Kn; jj++) m = fmaxf(m, acc[jj]);
  float s = 0.f;
  #pragma unroll
  for (int jj = 0; jj < Kn; jj++) { acc[jj] = __expf(acc[jj] - m); s += acc[jj]; }
  float inv = 1.f / s;
  int rg = (int)row0 + tid;          // h row index = t*Bn + b
  int b = rg & 255, t = rg >> 8;
  float* op = out + ((size_t)b * Tn + t) * Kn;
  #pragma unroll
  for (int jj = 0; jj < Kn; jj++) op[jj] = acc[jj] * inv;
}

// ---------- CRF log-likelihood: one wave per batch row ----------
__global__ __launch_bounds__(64) void k_crf(const float* __restrict__ logits,
                                            const int* __restrict__ labels,
                                            const int* __restrict__ lens_i,
                                            const float* __restrict__ trans,
                                            float* __restrict__ out_ll) {
  int b = blockIdx.x, lane = threadIdx.x;
  int len = lens_i[b];
  const float* lg = logits + (size_t)b * Tn * Kn;
  const int* lab = labels + (size_t)b * Tn;
  float sc = 0.f;
  for (int t = lane; t < Tn; t += 64) {
    if (t < len) {
      sc += lg[t * Kn + lab[t]];
      if (t >= 1) sc += trans[lab[t - 1] * Kn + lab[t]];
    }
  }
  for (int off = 32; off; off >>= 1) sc += __shfl_down(sc, off);
  bool act = lane < Kn;
  int jl = act ? lane : 0;
  float etr[Kn];
  #pragma unroll
  for (int i = 0; i < Kn; i++) etr[i] = __expf(trans[i * Kn + jl]);
  float a = act ? lg[jl] : -INFINITY;
  float lgv = (len > 1) ? lg[Kn + jl] : 0.f;
  for (int t = 1; t < len; t++) {
    float lgn = (t + 1 < len) ? lg[(t + 1) * Kn + jl] : 0.f;
    float m = a;
    for (int off = 8; off; off >>= 1) m = fmaxf(m, __shfl_xor(m, off, 16));
    float ea = __expf(a - m);
    float s = 0.f;
    #pragma unroll
    for (int i = 0; i < Kn; i++) s = fmaf(__shfl(ea, i), etr[i], s);
    float anew = m + __logf(s) + lgv;
    if (act) a = anew;
    lgv = lgn;
  }
  float m2 = a;
  for (int off = 8; off; off >>= 1) m2 = fmaxf(m2, __shfl_xor(m2, off, 16));
  float ea2 = act ? __expf(a - m2) : 0.f;
  float ssum = ea2;
  for (int off = 8; off; off >>= 1) ssum += __shfl_xor(ssum, off, 16);
  float logZ = m2 + __logf(ssum);
  if (lane == 0) out_ll[b] = sc - logZ;
}

extern "C" void kernel_launch(void* const* d_in, const int* in_sizes, int n_in,
                              void* d_out, int out_size, void* d_ws, size_t ws_size,
                              hipStream_t stream) {
  const int* text = (const int*)d_in[0];
  const int* labels = (const int*)d_in[1];
  const float* emb = (const float*)d_in[2];
  const float* Wf = (const float*)d_in[3];
  const float* Uf = (const float*)d_in[4];
  const float* bf_ = (const float*)d_in[5];
  const float* Wb = (const float*)d_in[6];
  const float* Ub = (const float*)d_in[7];
  const float* bb_ = (const float*)d_in[8];
  const float* Wd = (const float*)d_in[9];
  const float* bd = (const float*)d_in[10];
  const float* trans = (const float*)d_in[11];
  (void)in_sizes; (void)n_in; (void)out_size; (void)ws_size;

  float* out = (float*)d_out;
  float* out_logits = out;                       // [BT*K]
  float* out_lens = out + (size_t)BT * Kn;       // [B]
  float* out_ll = out_lens + Bn;                 // [B]

  char* ws = (char*)d_ws;
  size_t o = 0;
  int* lens_i = (int*)(ws + o);                o += 1024;
  unsigned short* wt = (unsigned short*)(ws + o);  o += (size_t)2 * G4 * 128 * 2;
  unsigned short* ut = (unsigned short*)(ws + o);  o += (size_t)2 * G4 * 128 * 2;
  unsigned short* xg = (unsigned short*)(ws + o);  o += (size_t)BT * 128 * 2;
  unsigned short* xw_s = (unsigned short*)(ws + o); o += (size_t)2 * BT * G4 * 2;  // [dir][t][bg][tid][16]
  unsigned short* hfb = (unsigned short*)(ws + o); o += (size_t)BT * Hn * 2;       // [t][b][128]
  unsigned short* hbb = (unsigned short*)(ws + o); o += (size_t)BT * Hn * 2;
  unsigned short* xwf = xw_s;
  unsigned short* xwb = xw_s + (size_t)BT * G4;

  hipLaunchKernelGGL(k_lens, dim3(Bn), dim3(64), 0, stream, text, lens_i, out_lens);
  hipLaunchKernelGGL(k_wt, dim3(1024), dim3(256), 0, stream, Wf, Wb, Uf, Ub, wt, ut);
  hipLaunchKernelGGL(k_gather, dim3(400), dim3(256), 0, stream, text, emb, xg);
  hipLaunchKernelGGL(k_gemm_xw, dim3(400, 8), dim3(256), 0, stream, xg, wt, bf_, bb_, xwf, xwb);
  hipLaunchKernelGGL(k_scan, dim3(32), dim3(512), 0, stream, ut, xw_s, hfb, hbb);
  hipLaunchKernelGGL(k_logits, dim3(400), dim3(128), 0, stream, hfb, hbb, Wd, bd, out_logits);
  hipLaunchKernelGGL(k_crf, dim3(Bn), dim3(64), 0, stream, out_logits, labels, lens_i, trans, out_ll);
}

// Round 11
// 297.740 us; speedup vs baseline: 1.6872x; 1.6872x over previous
//
#include <hip/hip_runtime.h>
#include <hip/hip_bf16.h>

#define Bn 256
#define Tn 200
#define En 100
#define Hn 128
#define Kn 13
#define G4 512          // 4H
#define BT 51200        // B*T

typedef __attribute__((ext_vector_type(8))) __bf16 bf8_t;
typedef __attribute__((ext_vector_type(4))) unsigned short us4_t;
typedef __attribute__((ext_vector_type(4))) float f4_t;

__device__ __forceinline__ unsigned short f2bf(float f) {
  unsigned int u = __float_as_uint(f);
  u = (u + 0x7FFFu + ((u >> 16) & 1u)) >> 16;
  return (unsigned short)u;
}
__device__ __forceinline__ float bf2f(unsigned short s) {
  return __uint_as_float(((unsigned int)s) << 16);
}
__device__ __forceinline__ float sigm(float x) { return 1.f / (1.f + __expf(-x)); }

// LDS-only barrier: drains lgkmcnt but lets VMEM stay in flight across it.
__device__ __forceinline__ void bar_lgkm() {
  asm volatile("s_waitcnt lgkmcnt(0)" ::: "memory");
  __builtin_amdgcn_s_barrier();
  __builtin_amdgcn_sched_barrier(0);
}

// Gate permutation: permuted col n holds original col g*128 + j with
// g=(n>>4)&3 = nt, j=(n>>6)*16+(n&15) = w*16+lr -> gates i,f,g,o of unit j
// land in one scan lane's acc0..3.
__device__ __forceinline__ int gperm(int n) {
  return ((n >> 4) & 3) * 128 + ((n >> 6) << 4) + (n & 15);
}

// ---------- lens ----------
__global__ __launch_bounds__(64) void k_lens(const int* __restrict__ text,
                                             int* __restrict__ lens_i,
                                             float* __restrict__ out_lens) {
  int b = blockIdx.x, lane = threadIdx.x;
  int cnt = 0;
  for (int t = lane; t < Tn; t += 64) cnt += (text[b * Tn + t] != 0);
  for (int off = 32; off; off >>= 1) cnt += __shfl_down(cnt, off);
  if (lane == 0) { lens_i[b] = cnt; out_lens[b] = (float)cnt; }
}

// ---------- W,U -> permuted-transposed bf16: wt[2][512][128], ut[2][512][128] ----------
__global__ __launch_bounds__(256) void k_wt(const float* __restrict__ Wf,
                                            const float* __restrict__ Wb,
                                            const float* __restrict__ Uf,
                                            const float* __restrict__ Ub,
                                            unsigned short* __restrict__ wt,
                                            unsigned short* __restrict__ ut) {
  int idx = blockIdx.x * 256 + threadIdx.x;   // 0..262143
  int half = idx >> 17;                        // 0:W  1:U
  int rem = idx & 131071;
  int dir = rem >> 16;
  int nk = rem & 65535;
  int n = nk >> 7, k = nk & 127;
  int mc = gperm(n);
  if (half == 0) {
    const float* W = dir ? Wb : Wf;
    wt[rem] = f2bf((k < En) ? W[k * G4 + mc] : 0.f);
  } else {
    const float* U = dir ? Ub : Uf;
    ut[rem] = f2bf(U[k * G4 + mc]);
  }
}

// ---------- embedding gather -> bf16 padded x[BT][128] ----------
__global__ __launch_bounds__(256) void k_gather(const int* __restrict__ text,
                                                const float* __restrict__ emb,
                                                unsigned short* __restrict__ xg) {
  int row = blockIdx.x * 128 + (threadIdx.x >> 1);
  int half = threadIdx.x & 1;
  int tok = text[row];
  const float* er = emb + (size_t)tok * En;
  unsigned short* xr = xg + (size_t)row * 128 + half * 64;
  #pragma unroll
  for (int c = 0; c < 64; c += 2) {
    int col = half * 64 + c;
    float v0 = (col < En) ? er[col] : 0.f;
    float v1 = (col + 1 < En) ? er[col + 1] : 0.f;
    unsigned int pk = (unsigned int)f2bf(v0) | ((unsigned int)f2bf(v1) << 16);
    *(unsigned int*)(xr + c) = pk;
  }
}

// ---------- xw = x@Wperm + bperm, stored SCAN-NATIVE: [t][bg(64)][tid(512)][4] ----------
// Scan thread tid = w*64+lg*16+lr handles batch b = bg*4+lg, unit jj=w*16+lr;
// its 4 gate pre-activations for step t live at [t][bg][tid][0..3] (8B chunk).
// Epilogue algebra: colg=nt*128+wn*64+n*16+lr -> w2=nt*2+wn, slot=n, lr2=lr
// (no carries since n*16+lr<64) -> the 4 n-values are one contiguous us4 store.
__global__ __launch_bounds__(256) void k_gemm_xw(const unsigned short* __restrict__ xg,
                                                 const unsigned short* __restrict__ wt,
                                                 const float* __restrict__ biasf,
                                                 const float* __restrict__ biasb,
                                                 unsigned short* __restrict__ xwf,
                                                 unsigned short* __restrict__ xwb) {
  __shared__ unsigned short As[128 * 128];
  __shared__ unsigned short Bs[128 * 128];
  int mt = blockIdx.x;              // 0..399
  int dir = blockIdx.y >> 2;        // 0=f,1=b
  int nt = blockIdx.y & 3;          // 0..3 (128-wide N tiles)
  const float* bias = dir ? biasb : biasf;
  unsigned short* out = dir ? xwb : xwf;
  int tid = threadIdx.x;
  const unsigned short* wt_d = wt + (size_t)dir * (G4 * 128);

  #pragma unroll
  for (int it = 0; it < 8; it++) {
    int idx = it * 256 + tid;
    int r = idx >> 4, c = idx & 15;
    bf8_t va = *(const bf8_t*)(xg + ((size_t)mt * 128 + r) * 128 + c * 8);
    bf8_t vb = *(const bf8_t*)(wt_d + ((size_t)nt * 128 + r) * 128 + c * 8);
    int byte = (r * 256 + c * 16) ^ ((r & 7) << 4);
    *(bf8_t*)((char*)As + byte) = va;
    *(bf8_t*)((char*)Bs + byte) = vb;
  }
  __syncthreads();
  int wid = tid >> 6, lane = tid & 63;
  int wm = wid >> 1, wn = wid & 1;
  int lr = lane & 15, lk = lane >> 4;
  f4_t zero = {0.f, 0.f, 0.f, 0.f};
  f4_t acc[4][4];
  #pragma unroll
  for (int m = 0; m < 4; m++)
    #pragma unroll
    for (int n = 0; n < 4; n++) acc[m][n] = zero;
  #pragma unroll
  for (int kk = 0; kk < 4; kk++) {
    bf8_t af[4], bv[4];
    #pragma unroll
    for (int m = 0; m < 4; m++) {
      int r = wm * 64 + m * 16 + lr;
      int byte = (r * 256 + kk * 64 + lk * 16) ^ ((r & 7) << 4);
      af[m] = *(const bf8_t*)((const char*)As + byte);
    }
    #pragma unroll
    for (int n = 0; n < 4; n++) {
      int r = wn * 64 + n * 16 + lr;
      int byte = (r * 256 + kk * 64 + lk * 16) ^ ((r & 7) << 4);
      bv[n] = *(const bf8_t*)((const char*)Bs + byte);
    }
    #pragma unroll
    for (int m = 0; m < 4; m++)
      #pragma unroll
      for (int n = 0; n < 4; n++)
        acc[m][n] = __builtin_amdgcn_mfma_f32_16x16x32_bf16(af[m], bv[n], acc[m][n], 0, 0, 0);
  }
  float bn[4];
  #pragma unroll
  for (int n = 0; n < 4; n++) {
    int colg = nt * 128 + wn * 64 + n * 16 + lr;
    bn[n] = bias[gperm(colg)];
  }
  int w2 = nt * 2 + wn;
  #pragma unroll
  for (int m = 0; m < 4; m++) {
    int rowl = wm * 64 + m * 16 + lk * 4;
    #pragma unroll
    for (int q = 0; q < 4; q++) {
      int row = mt * 128 + rowl + q;
      int b = row / 200;
      int t = row - b * 200;
      int bg = b >> 2, lg2 = b & 3;
      int tid2 = w2 * 64 + lg2 * 16 + lr;
      size_t dst = (((size_t)t * 64 + bg) * 512 + tid2) * 4;
      us4_t v;
      v[0] = f2bf(acc[m][0][q] + bn[0]);
      v[1] = f2bf(acc[m][1][q] + bn[1]);
      v[2] = f2bf(acc[m][2][q] + bn[2]);
      v[3] = f2bf(acc[m][3][q] + bn[3]);
      *(us4_t*)(out + dst) = v;
    }
  }
}

// ---------- recurrent scan, MFMA version (R11: 128 blocks, 4 rows/block) ----------
// R10 post-mortem: VALUBusy 9.2% chip = ~74% on the 32 ACTIVE CUs -> the scan
// was VALU-ISSUE-bound while 224 CUs idled. R11 spreads batch over 128 blocks
// (4 rows each) and places the 4 rows at MFMA D-rows {0,4,8,12} (lg*4, q=0):
// every lane owns exactly one (row, unit) -> gates x1/thread, AINIT = 4 bf2f,
// zero divergence. Unused A-rows stay zero in LDS, so garbage D-rows are
// stable and acc[1..3] init once. U stays AGPR-pinned; per-SIMD VALU ~10x down.
#define UB16(M) M(0,0) M(0,1) M(0,2) M(0,3) M(1,0) M(1,1) M(1,2) M(1,3) \
                M(2,0) M(2,1) M(2,2) M(2,3) M(3,0) M(3,1) M(3,2) M(3,3)

__global__ __attribute__((amdgpu_flat_work_group_size(512, 512),
                          amdgpu_waves_per_eu(1, 2)))
void k_scan(const unsigned short* __restrict__ ut,
            const unsigned short* __restrict__ xw2,
            unsigned short* __restrict__ hf,
            unsigned short* __restrict__ hb) {
  int blk = blockIdx.x;              // 0..127
  int dir = blk >> 6;
  int bg = blk & 63;
  int b0 = bg * 4;
  int tid = threadIdx.x;
  int w = tid >> 6, l = tid & 63;
  int lr = l & 15, lg = l >> 4;
  int jj = w * 16 + lr;
  const unsigned short* ut_d = ut + (size_t)dir * (G4 * 128);
  const unsigned short* xw_d = xw2 + (size_t)dir * ((size_t)BT * G4);
  unsigned short* hout = dir ? hb : hf;
  int t0 = dir ? (Tn - 1) : 0;
  int dt = dir ? -1 : 1;

  // U B-frags pinned into AGPRs: frag(nt,kk) = cols w*64+nt*16+lr, k=kk*32+lg*8..+7
#define LOADUB(nt, kk) \
  bf8_t ub_##nt##_##kk = *(const bf8_t*)(ut_d + (size_t)(w * 64 + (nt) * 16 + lr) * 128 + (kk) * 32 + lg * 8); \
  asm volatile("" : "+a"(ub_##nt##_##kk));
  UB16(LOADUB)
#undef LOADUB

  __shared__ unsigned short h_lds[2][2048];   // two 4KB halves, XOR-swizzled rows
  for (int i = tid; i < 2048; i += 512) ((unsigned int*)h_lds)[i] = 0;  // zero BOTH buffers

  // A-frag read addrs (rows = lr, k-offset = kk*32+lg*8 bf16) in buf0
  int rb0 = (lr * 256 +   0 + lg * 16) ^ ((lr & 7) << 4);
  int rb1 = (lr * 256 +  64 + lg * 16) ^ ((lr & 7) << 4);
  int rb2 = (lr * 256 + 128 + lg * 16) ^ ((lr & 7) << 4);
  int rb3 = (lr * 256 + 192 + lg * 16) ^ ((lr & 7) << 4);
  // h write addr: row lg*4 (D-row of this lane's batch row), col jj, buf1 first
  int wb = (((lg * 4) * 256 + jj * 2) ^ (((lg * 4) & 7) << 4)) + 4096;
  char* lbase = (char*)h_lds;

  const unsigned short* xptr = xw_d + (((size_t)t0 * 64 + bg) * 512 + tid) * 4;
  const long long xstep = (long long)dt * 131072;     // 64*512*4 u16 per t
  unsigned short* hp = hout + ((size_t)t0 * Bn + b0 + lg) * 128 + jj;
  const long long hstep = (long long)dt * Bn * 128;

  // depth-2 prefetch
  us4_t xa = *(const us4_t*)(xptr);
  us4_t xb = *(const us4_t*)(xptr + xstep);
  xptr += 2 * xstep;

  float c0 = 0.f;
  f4_t acc0 = {0.f,0.f,0.f,0.f}, acc1 = {0.f,0.f,0.f,0.f};
  f4_t acc2 = {0.f,0.f,0.f,0.f}, acc3 = {0.f,0.f,0.f,0.f};
  bar_lgkm();

#define MF(nt, kk) acc##nt = __builtin_amdgcn_mfma_f32_16x16x32_bf16(af##kk, ub_##nt##_##kk, acc##nt, 0, 0, 0);
#define STEP(X, ISSUE_OK) { \
    acc0[0] = bf2f(X[0]); acc1[0] = bf2f(X[1]); \
    acc2[0] = bf2f(X[2]); acc3[0] = bf2f(X[3]); \
    if (ISSUE_OK) { X = *(const us4_t*)(xptr); } \
    xptr += xstep; \
    bf8_t af0 = *(const bf8_t*)(lbase + rb0); \
    bf8_t af1 = *(const bf8_t*)(lbase + rb1); \
    bf8_t af2 = *(const bf8_t*)(lbase + rb2); \
    bf8_t af3 = *(const bf8_t*)(lbase + rb3); \
    MF(0,0) MF(1,0) MF(2,0) MF(3,0) \
    MF(0,1) MF(1,1) MF(2,1) MF(3,1) \
    MF(0,2) MF(1,2) MF(2,2) MF(3,2) \
    MF(0,3) MF(1,3) MF(2,3) MF(3,3) \
    float ig = sigm(acc0[0]); \
    float fg = sigm(acc1[0]); \
    float gg = fmaxf(acc2[0], 0.f); \
    c0 = fmaf(fg, c0, ig * gg); \
    unsigned short hs2 = f2bf(sigm(acc3[0]) * fmaxf(c0, 0.f)); \
    *(unsigned short*)(lbase + wb) = hs2; \
    bar_lgkm(); \
    hp[0] = hs2; \
    rb0 ^= 4096; rb1 ^= 4096; rb2 ^= 4096; rb3 ^= 4096; wb ^= 4096; \
    hp += hstep; }

  for (int tt = 0; tt < Tn; tt += 2) {
    STEP(xa, tt < Tn - 2)
    STEP(xb, tt < Tn - 3)
  }
#undef STEP
#undef MF
}

// ---------- logits = softmax([hf|hb] @ Wd + bd); h rows are (t*Bn+b) ----------
__global__ __launch_bounds__(128) void k_logits(const unsigned short* __restrict__ hf,
                                                const unsigned short* __restrict__ hb,
                                                const float* __restrict__ Wd,
                                                const float* __restrict__ bd,
                                                float* __restrict__ out) {
  __shared__ unsigned short hs[128 * 256];   // 64KB, XOR-swizzled rows of 512B
  int tid = threadIdx.x;
  size_t row0 = (size_t)blockIdx.x * 128;
  #pragma unroll
  for (int it = 0; it < 16; it++) {
    int idx = it * 128 + tid;
    int r = idx >> 4, c = idx & 15;
    bf8_t vf = *(const bf8_t*)(hf + (row0 + r) * 128 + c * 8);
    bf8_t vb = *(const bf8_t*)(hb + (row0 + r) * 128 + c * 8);
    int byte = (r * 512 + c * 16) ^ ((r & 7) << 4);
    *(bf8_t*)((char*)hs + byte) = vf;
    int byte2 = (r * 512 + 256 + c * 16) ^ ((r & 7) << 4);
    *(bf8_t*)((char*)hs + byte2) = vb;
  }
  __syncthreads();
  float acc[Kn];
  #pragma unroll
  for (int jj = 0; jj < Kn; jj++) acc[jj] = bd[jj];
  int r = tid;
  #pragma unroll 4
  for (int c = 0; c < 32; c++) {
    int byte = (r * 512 + c * 16) ^ ((r & 7) << 4);
    bf8_t v = *(const bf8_t*)((const char*)hs + byte);
    #pragma unroll
    for (int e = 0; e < 8; e++) {
      float h = (float)v[e];
      int k = c * 8 + e;
      #pragma unroll
      for (int jj = 0; jj < Kn; jj++)
        acc[jj] = fmaf(h, Wd[k * Kn + jj], acc[jj]);   // uniform -> scalar loads
    }
  }
  float m = acc[0];
  #pragma unroll
  for (int jj = 1; jj < Kn; jj++) m = fmaxf(m, acc[jj]);
  float s = 0.f;
  #pragma unroll
  for (int jj = 0; jj < Kn; jj++) { acc[jj] = __expf(acc[jj] - m); s += acc[jj]; }
  float inv = 1.f / s;
  int rg = (int)row0 + tid;          // h row index = t*Bn + b
  int b = rg & 255, t = rg >> 8;
  float* op = out + ((size_t)b * Tn + t) * Kn;
  #pragma unroll
  for (int jj = 0; jj < Kn; jj++) op[jj] = acc[jj] * inv;
}

// ---------- CRF log-likelihood: one wave per batch row ----------
__global__ __launch_bounds__(64) void k_crf(const float* __restrict__ logits,
                                            const int* __restrict__ labels,
                                            const int* __restrict__ lens_i,
                                            const float* __restrict__ trans,
                                            float* __restrict__ out_ll) {
  int b = blockIdx.x, lane = threadIdx.x;
  int len = lens_i[b];
  const float* lg = logits + (size_t)b * Tn * Kn;
  const int* lab = labels + (size_t)b * Tn;
  float sc = 0.f;
  for (int t = lane; t < Tn; t += 64) {
    if (t < len) {
      sc += lg[t * Kn + lab[t]];
      if (t >= 1) sc += trans[lab[t - 1] * Kn + lab[t]];
    }
  }
  for (int off = 32; off; off >>= 1) sc += __shfl_down(sc, off);
  bool act = lane < Kn;
  int jl = act ? lane : 0;
  float etr[Kn];
  #pragma unroll
  for (int i = 0; i < Kn; i++) etr[i] = __expf(trans[i * Kn + jl]);
  float a = act ? lg[jl] : -INFINITY;
  float lgv = (len > 1) ? lg[Kn + jl] : 0.f;
  for (int t = 1; t < len; t++) {
    float lgn = (t + 1 < len) ? lg[(t + 1) * Kn + jl] : 0.f;
    float m = a;
    for (int off = 8; off; off >>= 1) m = fmaxf(m, __shfl_xor(m, off, 16));
    float ea = __expf(a - m);
    float s = 0.f;
    #pragma unroll
    for (int i = 0; i < Kn; i++) s = fmaf(__shfl(ea, i), etr[i], s);
    float anew = m + __logf(s) + lgv;
    if (act) a = anew;
    lgv = lgn;
  }
  float m2 = a;
  for (int off = 8; off; off >>= 1) m2 = fmaxf(m2, __shfl_xor(m2, off, 16));
  float ea2 = act ? __expf(a - m2) : 0.f;
  float ssum = ea2;
  for (int off = 8; off; off >>= 1) ssum += __shfl_xor(ssum, off, 16);
  float logZ = m2 + __logf(ssum);
  if (lane == 0) out_ll[b] = sc - logZ;
}

extern "C" void kernel_launch(void* const* d_in, const int* in_sizes, int n_in,
                              void* d_out, int out_size, void* d_ws, size_t ws_size,
                              hipStream_t stream) {
  const int* text = (const int*)d_in[0];
  const int* labels = (const int*)d_in[1];
  const float* emb = (const float*)d_in[2];
  const float* Wf = (const float*)d_in[3];
  const float* Uf = (const float*)d_in[4];
  const float* bf_ = (const float*)d_in[5];
  const float* Wb = (const float*)d_in[6];
  const float* Ub = (const float*)d_in[7];
  const float* bb_ = (const float*)d_in[8];
  const float* Wd = (const float*)d_in[9];
  const float* bd = (const float*)d_in[10];
  const float* trans = (const float*)d_in[11];
  (void)in_sizes; (void)n_in; (void)out_size; (void)ws_size;

  float* out = (float*)d_out;
  float* out_logits = out;                       // [BT*K]
  float* out_lens = out + (size_t)BT * Kn;       // [B]
  float* out_ll = out_lens + Bn;                 // [B]

  char* ws = (char*)d_ws;
  size_t o = 0;
  int* lens_i = (int*)(ws + o);                o += 1024;
  unsigned short* wt = (unsigned short*)(ws + o);  o += (size_t)2 * G4 * 128 * 2;
  unsigned short* ut = (unsigned short*)(ws + o);  o += (size_t)2 * G4 * 128 * 2;
  unsigned short* xg = (unsigned short*)(ws + o);  o += (size_t)BT * 128 * 2;
  unsigned short* xw_s = (unsigned short*)(ws + o); o += (size_t)2 * BT * G4 * 2;  // [dir][t][bg][tid][4]
  unsigned short* hfb = (unsigned short*)(ws + o); o += (size_t)BT * Hn * 2;       // [t][b][128]
  unsigned short* hbb = (unsigned short*)(ws + o); o += (size_t)BT * Hn * 2;
  unsigned short* xwf = xw_s;
  unsigned short* xwb = xw_s + (size_t)BT * G4;

  hipLaunchKernelGGL(k_lens, dim3(Bn), dim3(64), 0, stream, text, lens_i, out_lens);
  hipLaunchKernelGGL(k_wt, dim3(1024), dim3(256), 0, stream, Wf, Wb, Uf, Ub, wt, ut);
  hipLaunchKernelGGL(k_gather, dim3(400), dim3(256), 0, stream, text, emb, xg);
  hipLaunchKernelGGL(k_gemm_xw, dim3(400, 8), dim3(256), 0, stream, xg, wt, bf_, bb_, xwf, xwb);
  hipLaunchKernelGGL(k_scan, dim3(128), dim3(512), 0, stream, ut, xw_s, hfb, hbb);
  hipLaunchKernelGGL(k_logits, dim3(400), dim3(128), 0, stream, hfb, hbb, Wd, bd, out_logits);
  hipLaunchKernelGGL(k_crf, dim3(Bn), dim3(64), 0, stream, out_logits, labels, lens_i, trans, out_ll);
}

// Round 12
// 288.913 us; speedup vs baseline: 1.7388x; 1.0306x over previous
//
#include <hip/hip_runtime.h>
#include <hip/hip_bf16.h>

#define Bn 256
#define Tn 200
#define En 100
#define Hn 128
#define Kn 13
#define G4 512          // 4H
#define BT 51200        // B*T

typedef __attribute__((ext_vector_type(8))) __bf16 bf8_t;
typedef __attribute__((ext_vector_type(4))) unsigned short us4_t;
typedef __attribute__((ext_vector_type(4))) float f4_t;

__device__ __forceinline__ unsigned short f2bf(float f) {
  unsigned int u = __float_as_uint(f);
  u = (u + 0x7FFFu + ((u >> 16) & 1u)) >> 16;
  return (unsigned short)u;
}
__device__ __forceinline__ float bf2f(unsigned short s) {
  return __uint_as_float(((unsigned int)s) << 16);
}
__device__ __forceinline__ float sigm(float x) { return 1.f / (1.f + __expf(-x)); }

// LDS-only barrier: drains lgkmcnt but lets VMEM stay in flight across it.
__device__ __forceinline__ void bar_lgkm() {
  asm volatile("s_waitcnt lgkmcnt(0)" ::: "memory");
  __builtin_amdgcn_s_barrier();
  __builtin_amdgcn_sched_barrier(0);
}

// Gate permutation: permuted col n holds original col g*128 + j with
// g=(n>>4)&3, j=(n>>6)*16+(n&15) -> gates i,f,g,o of unit j land in one
// scan lane's 4 slots.
__device__ __forceinline__ int gperm(int n) {
  return ((n >> 4) & 3) * 128 + ((n >> 6) << 4) + (n & 15);
}

// ---------- prep: wt/ut transpose-permute (blocks 0..1023) + lens (1024..1087) ----------
__global__ __launch_bounds__(256) void k_prep(const int* __restrict__ text,
                                              const float* __restrict__ Wf,
                                              const float* __restrict__ Wb,
                                              const float* __restrict__ Uf,
                                              const float* __restrict__ Ub,
                                              unsigned short* __restrict__ wt,
                                              unsigned short* __restrict__ ut,
                                              int* __restrict__ lens_i,
                                              float* __restrict__ out_lens) {
  int bx = blockIdx.x;
  if (bx < 1024) {
    int idx = bx * 256 + threadIdx.x;   // 0..262143
    int half = idx >> 17;               // 0:W  1:U
    int rem = idx & 131071;
    int dir = rem >> 16;
    int nk = rem & 65535;
    int n = nk >> 7, k = nk & 127;
    int mc = gperm(n);
    if (half == 0) {
      const float* W = dir ? Wb : Wf;
      wt[rem] = f2bf((k < En) ? W[k * G4 + mc] : 0.f);
    } else {
      const float* U = dir ? Ub : Uf;
      ut[rem] = f2bf(U[k * G4 + mc]);
    }
  } else {
    int wi = threadIdx.x >> 6, lane = threadIdx.x & 63;
    int b = (bx - 1024) * 4 + wi;
    int cnt = 0;
    for (int t = lane; t < Tn; t += 64) cnt += (text[b * Tn + t] != 0);
    for (int off = 32; off; off >>= 1) cnt += __shfl_down(cnt, off);
    if (lane == 0) { lens_i[b] = cnt; out_lens[b] = (float)cnt; }
  }
}

// ---------- xw = gather(emb,text)@Wperm + bperm, scan-native out [t][bg][tid][4] ----------
// 1600 blocks (dir*800 + mt), 512 thr (8 waves), 64-row M-tile staged ONCE from
// emb directly (no xg intermediate). B = 16 register frags from L2-hot wt.
// Wave w covers permuted cols w*64..w*64+63; epilogue algebra: colg =
// w*64+n*16+lr -> gate g = n, scan-w2 = w, lr2 = lr (w*4===0 mod 4).
#define NB16(M) M(0,0) M(0,1) M(0,2) M(0,3) M(1,0) M(1,1) M(1,2) M(1,3) \
                M(2,0) M(2,1) M(2,2) M(2,3) M(3,0) M(3,1) M(3,2) M(3,3)

__global__ __launch_bounds__(512) void k_gemm_xw(const int* __restrict__ text,
                                                 const float* __restrict__ emb,
                                                 const unsigned short* __restrict__ wt,
                                                 const float* __restrict__ biasf,
                                                 const float* __restrict__ biasb,
                                                 unsigned short* __restrict__ xwf,
                                                 unsigned short* __restrict__ xwb) {
  __shared__ unsigned short As[64 * 128];   // 16KB, XOR-swizzled rows of 256B
  int bx = blockIdx.x;              // 0..1599
  int dir = (bx >= 800);
  int mt = dir ? bx - 800 : bx;     // 0..799 (64-row tiles)
  const float* bias = dir ? biasb : biasf;
  unsigned short* out = dir ? xwb : xwf;
  int tid = threadIdx.x;
  const unsigned short* wt_d = wt + (size_t)dir * (G4 * 128);

  // --- stage A (64 x 128 bf16) from emb via text: 8 thr/row, 16 cols each ---
  {
    int row = tid >> 3;             // 0..63
    int oct = tid & 7;              // cols oct*16..oct*16+15
    int tok = text[mt * 64 + row];
    const float* er = emb + (size_t)tok * En;
    float fv[16];
    #pragma unroll
    for (int i = 0; i < 16; i++) fv[i] = 0.f;
    if (oct < 6) {
      #pragma unroll
      for (int i = 0; i < 4; i++) {
        float4 v = *(const float4*)(er + oct * 16 + i * 4);
        fv[i * 4 + 0] = v.x; fv[i * 4 + 1] = v.y; fv[i * 4 + 2] = v.z; fv[i * 4 + 3] = v.w;
      }
    } else if (oct == 6) {
      float4 v = *(const float4*)(er + 96);   // cols 96..99, rest pad
      fv[0] = v.x; fv[1] = v.y; fv[2] = v.z; fv[3] = v.w;
    }
    int swz = (row & 7) << 4;
    #pragma unroll
    for (int j = 0; j < 2; j++) {
      unsigned short pk[8];
      #pragma unroll
      for (int e = 0; e < 8; e++) pk[e] = f2bf(fv[j * 8 + e]);
      int byte = (row * 256 + oct * 32 + j * 16) ^ swz;
      *(bf8_t*)((char*)As + byte) = *(bf8_t*)pk;
    }
  }

  int w = tid >> 6, l = tid & 63;
  int lr = l & 15, lg = l >> 4, lk = lg;
  // B-frags from global (L2-hot): frag(n,kk) = cols w*64+n*16+lr, k=kk*32+lg*8..+7
#define LOADB(n, kk) \
  bf8_t bb_##n##_##kk = *(const bf8_t*)(wt_d + (size_t)(w * 64 + (n) * 16 + lr) * 128 + (kk) * 32 + lg * 8);
  NB16(LOADB)
#undef LOADB
  __syncthreads();

  f4_t zero = {0.f, 0.f, 0.f, 0.f};
  f4_t acc[4][4];
  #pragma unroll
  for (int m = 0; m < 4; m++)
    #pragma unroll
    for (int n = 0; n < 4; n++) acc[m][n] = zero;

  const char* lAs = (const char*)As;
  int sz = (lr & 7) << 4;
#define MFK(kk) { \
    bf8_t a0 = *(const bf8_t*)(lAs + (((0 * 16 + lr) * 256 + (kk) * 64 + lg * 16) ^ sz)); \
    bf8_t a1 = *(const bf8_t*)(lAs + (((1 * 16 + lr) * 256 + (kk) * 64 + lg * 16) ^ sz)); \
    bf8_t a2 = *(const bf8_t*)(lAs + (((2 * 16 + lr) * 256 + (kk) * 64 + lg * 16) ^ sz)); \
    bf8_t a3 = *(const bf8_t*)(lAs + (((3 * 16 + lr) * 256 + (kk) * 64 + lg * 16) ^ sz)); \
    acc[0][0] = __builtin_amdgcn_mfma_f32_16x16x32_bf16(a0, bb_0_##kk, acc[0][0], 0, 0, 0); \
    acc[0][1] = __builtin_amdgcn_mfma_f32_16x16x32_bf16(a0, bb_1_##kk, acc[0][1], 0, 0, 0); \
    acc[0][2] = __builtin_amdgcn_mfma_f32_16x16x32_bf16(a0, bb_2_##kk, acc[0][2], 0, 0, 0); \
    acc[0][3] = __builtin_amdgcn_mfma_f32_16x16x32_bf16(a0, bb_3_##kk, acc[0][3], 0, 0, 0); \
    acc[1][0] = __builtin_amdgcn_mfma_f32_16x16x32_bf16(a1, bb_0_##kk, acc[1][0], 0, 0, 0); \
    acc[1][1] = __builtin_amdgcn_mfma_f32_16x16x32_bf16(a1, bb_1_##kk, acc[1][1], 0, 0, 0); \
    acc[1][2] = __builtin_amdgcn_mfma_f32_16x16x32_bf16(a1, bb_2_##kk, acc[1][2], 0, 0, 0); \
    acc[1][3] = __builtin_amdgcn_mfma_f32_16x16x32_bf16(a1, bb_3_##kk, acc[1][3], 0, 0, 0); \
    acc[2][0] = __builtin_amdgcn_mfma_f32_16x16x32_bf16(a2, bb_0_##kk, acc[2][0], 0, 0, 0); \
    acc[2][1] = __builtin_amdgcn_mfma_f32_16x16x32_bf16(a2, bb_1_##kk, acc[2][1], 0, 0, 0); \
    acc[2][2] = __builtin_amdgcn_mfma_f32_16x16x32_bf16(a2, bb_2_##kk, acc[2][2], 0, 0, 0); \
    acc[2][3] = __builtin_amdgcn_mfma_f32_16x16x32_bf16(a2, bb_3_##kk, acc[2][3], 0, 0, 0); \
    acc[3][0] = __builtin_amdgcn_mfma_f32_16x16x32_bf16(a3, bb_0_##kk, acc[3][0], 0, 0, 0); \
    acc[3][1] = __builtin_amdgcn_mfma_f32_16x16x32_bf16(a3, bb_1_##kk, acc[3][1], 0, 0, 0); \
    acc[3][2] = __builtin_amdgcn_mfma_f32_16x16x32_bf16(a3, bb_2_##kk, acc[3][2], 0, 0, 0); \
    acc[3][3] = __builtin_amdgcn_mfma_f32_16x16x32_bf16(a3, bb_3_##kk, acc[3][3], 0, 0, 0); }
  MFK(0) MFK(1) MFK(2) MFK(3)
#undef MFK

  float bn[4];
  #pragma unroll
  for (int n = 0; n < 4; n++) bn[n] = bias[gperm(w * 64 + n * 16 + lr)];
  #pragma unroll
  for (int m = 0; m < 4; m++) {
    int rowl = m * 16 + lk * 4;
    #pragma unroll
    for (int q = 0; q < 4; q++) {
      int row = mt * 64 + rowl + q;
      int b = row / 200;
      int t = row - b * 200;
      int bg = b >> 2, lg2 = b & 3;
      int tid2 = w * 64 + lg2 * 16 + lr;
      size_t dst = (((size_t)t * 64 + bg) * 512 + tid2) * 4;
      us4_t v;
      v[0] = f2bf(acc[m][0][q] + bn[0]);
      v[1] = f2bf(acc[m][1][q] + bn[1]);
      v[2] = f2bf(acc[m][2][q] + bn[2]);
      v[3] = f2bf(acc[m][3][q] + bn[3]);
      *(us4_t*)(out + dst) = v;
    }
  }
}

// ---------- recurrent scan (R12 = R11 + ds_read-first STEP, branch-free prefetch) ----------
#define UB16(M) M(0,0) M(0,1) M(0,2) M(0,3) M(1,0) M(1,1) M(1,2) M(1,3) \
                M(2,0) M(2,1) M(2,2) M(2,3) M(3,0) M(3,1) M(3,2) M(3,3)

__global__ __attribute__((amdgpu_flat_work_group_size(512, 512),
                          amdgpu_waves_per_eu(1, 2)))
void k_scan(const unsigned short* __restrict__ ut,
            const unsigned short* __restrict__ xw2,
            unsigned short* __restrict__ hf,
            unsigned short* __restrict__ hb) {
  int blk = blockIdx.x;              // 0..127
  int dir = blk >> 6;
  int bg = blk & 63;
  int b0 = bg * 4;
  int tid = threadIdx.x;
  int w = tid >> 6, l = tid & 63;
  int lr = l & 15, lg = l >> 4;
  int jj = w * 16 + lr;
  const unsigned short* ut_d = ut + (size_t)dir * (G4 * 128);
  const unsigned short* xw_d = xw2 + (size_t)dir * ((size_t)BT * G4);
  unsigned short* hout = dir ? hb : hf;
  int t0 = dir ? (Tn - 1) : 0;
  int dt = dir ? -1 : 1;

#define LOADUB(nt, kk) \
  bf8_t ub_##nt##_##kk = *(const bf8_t*)(ut_d + (size_t)(w * 64 + (nt) * 16 + lr) * 128 + (kk) * 32 + lg * 8); \
  asm volatile("" : "+a"(ub_##nt##_##kk));
  UB16(LOADUB)
#undef LOADUB

  __shared__ unsigned short h_lds[2][2048];   // two 4KB halves, XOR-swizzled rows
  for (int i = tid; i < 2048; i += 512) ((unsigned int*)h_lds)[i] = 0;

  int rb0 = (lr * 256 +   0 + lg * 16) ^ ((lr & 7) << 4);
  int rb1 = (lr * 256 +  64 + lg * 16) ^ ((lr & 7) << 4);
  int rb2 = (lr * 256 + 128 + lg * 16) ^ ((lr & 7) << 4);
  int rb3 = (lr * 256 + 192 + lg * 16) ^ ((lr & 7) << 4);
  int wb = (((lg * 4) * 256 + jj * 2) ^ (((lg * 4) & 7) << 4)) + 4096;
  char* lbase = (char*)h_lds;

  const unsigned short* xptr = xw_d + (((size_t)t0 * 64 + bg) * 512 + tid) * 4;
  const long long xstep = (long long)dt * 131072;     // 64*512*4 u16 per t
  unsigned short* hp = hout + ((size_t)t0 * Bn + b0 + lg) * 128 + jj;
  const long long hstep = (long long)dt * Bn * 128;

  us4_t xa = *(const us4_t*)(xptr);
  us4_t xb = *(const us4_t*)(xptr + xstep);
  xptr += 2 * xstep;

  float c0 = 0.f;
  f4_t acc0 = {0.f,0.f,0.f,0.f}, acc1 = {0.f,0.f,0.f,0.f};
  f4_t acc2 = {0.f,0.f,0.f,0.f}, acc3 = {0.f,0.f,0.f,0.f};
  bar_lgkm();

#define MF(nt, kk) acc##nt = __builtin_amdgcn_mfma_f32_16x16x32_bf16(af##kk, ub_##nt##_##kk, acc##nt, 0, 0, 0);
#define STEP(X) { \
    bf8_t af0 = *(const bf8_t*)(lbase + rb0); \
    bf8_t af1 = *(const bf8_t*)(lbase + rb1); \
    bf8_t af2 = *(const bf8_t*)(lbase + rb2); \
    bf8_t af3 = *(const bf8_t*)(lbase + rb3); \
    acc0[0] = bf2f(X[0]); acc1[0] = bf2f(X[1]); \
    acc2[0] = bf2f(X[2]); acc3[0] = bf2f(X[3]); \
    X = *(const us4_t*)(xptr);    /* unconditional; 2-step overrun lands in adjacent ws */ \
    xptr += xstep; \
    MF(0,0) MF(1,0) MF(2,0) MF(3,0) \
    MF(0,1) MF(1,1) MF(2,1) MF(3,1) \
    MF(0,2) MF(1,2) MF(2,2) MF(3,2) \
    MF(0,3) MF(1,3) MF(2,3) MF(3,3) \
    float ig = sigm(acc0[0]); \
    float fg = sigm(acc1[0]); \
    float gg = fmaxf(acc2[0], 0.f); \
    c0 = fmaf(fg, c0, ig * gg); \
    unsigned short hs2 = f2bf(sigm(acc3[0]) * fmaxf(c0, 0.f)); \
    *(unsigned short*)(lbase + wb) = hs2; \
    bar_lgkm(); \
    hp[0] = hs2; \
    rb0 ^= 4096; rb1 ^= 4096; rb2 ^= 4096; rb3 ^= 4096; wb ^= 4096; \
    hp += hstep; }

  for (int tt = 0; tt < Tn; tt += 2) {
    STEP(xa)
    STEP(xb)
  }
#undef STEP
#undef MF
}

// ---------- logits = softmax([hf|hb] @ Wd + bd); h rows are (t*Bn+b) ----------
__global__ __launch_bounds__(128) void k_logits(const unsigned short* __restrict__ hf,
                                                const unsigned short* __restrict__ hb,
                                                const float* __restrict__ Wd,
                                                const float* __restrict__ bd,
                                                float* __restrict__ out) {
  __shared__ unsigned short hs[128 * 256];   // 64KB, XOR-swizzled rows of 512B
  int tid = threadIdx.x;
  size_t row0 = (size_t)blockIdx.x * 128;
  #pragma unroll
  for (int it = 0; it < 16; it++) {
    int idx = it * 128 + tid;
    int r = idx >> 4, c = idx & 15;
    bf8_t vf = *(const bf8_t*)(hf + (row0 + r) * 128 + c * 8);
    bf8_t vb = *(const bf8_t*)(hb + (row0 + r) * 128 + c * 8);
    int byte = (r * 512 + c * 16) ^ ((r & 7) << 4);
    *(bf8_t*)((char*)hs + byte) = vf;
    int byte2 = (r * 512 + 256 + c * 16) ^ ((r & 7) << 4);
    *(bf8_t*)((char*)hs + byte2) = vb;
  }
  __syncthreads();
  float acc[Kn];
  #pragma unroll
  for (int jj = 0; jj < Kn; jj++) acc[jj] = bd[jj];
  int r = tid;
  #pragma unroll 4
  for (int c = 0; c < 32; c++) {
    int byte = (r * 512 + c * 16) ^ ((r & 7) << 4);
    bf8_t v = *(const bf8_t*)((const char*)hs + byte);
    #pragma unroll
    for (int e = 0; e < 8; e++) {
      float h = (float)v[e];
      int k = c * 8 + e;
      #pragma unroll
      for (int jj = 0; jj < Kn; jj++)
        acc[jj] = fmaf(h, Wd[k * Kn + jj], acc[jj]);   // uniform -> scalar loads
    }
  }
  float m = acc[0];
  #pragma unroll
  for (int jj = 1; jj < Kn; jj++) m = fmaxf(m, acc[jj]);
  float s = 0.f;
  #pragma unroll
  for (int jj = 0; jj < Kn; jj++) { acc[jj] = __expf(acc[jj] - m); s += acc[jj]; }
  float inv = 1.f / s;
  int rg = (int)row0 + tid;          // h row index = t*Bn + b
  int b = rg & 255, t = rg >> 8;
  float* op = out + ((size_t)b * Tn + t) * Kn;
  #pragma unroll
  for (int jj = 0; jj < Kn; jj++) op[jj] = acc[jj] * inv;
}

// ---------- CRF log-likelihood: one wave per batch row ----------
__global__ __launch_bounds__(64) void k_crf(const float* __restrict__ logits,
                                            const int* __restrict__ labels,
                                            const int* __restrict__ lens_i,
                                            const float* __restrict__ trans,
                                            float* __restrict__ out_ll) {
  int b = blockIdx.x, lane = threadIdx.x;
  int len = lens_i[b];
  const float* lg = logits + (size_t)b * Tn * Kn;
  const int* lab = labels + (size_t)b * Tn;
  float sc = 0.f;
  for (int t = lane; t < Tn; t += 64) {
    if (t < len) {
      sc += lg[t * Kn + lab[t]];
      if (t >= 1) sc += trans[lab[t - 1] * Kn + lab[t]];
    }
  }
  for (int off = 32; off; off >>= 1) sc += __shfl_down(sc, off);
  bool act = lane < Kn;
  int jl = act ? lane : 0;
  float etr[Kn];
  #pragma unroll
  for (int i = 0; i < Kn; i++) etr[i] = __expf(trans[i * Kn + jl]);
  float a = act ? lg[jl] : -INFINITY;
  float lgv = (len > 1) ? lg[Kn + jl] : 0.f;
  for (int t = 1; t < len; t++) {
    float lgn = (t + 1 < len) ? lg[(t + 1) * Kn + jl] : 0.f;
    float m = a;
    for (int off = 8; off; off >>= 1) m = fmaxf(m, __shfl_xor(m, off, 16));
    float ea = __expf(a - m);
    float s = 0.f;
    #pragma unroll
    for (int i = 0; i < Kn; i++) s = fmaf(__shfl(ea, i), etr[i], s);
    float anew = m + __logf(s) + lgv;
    if (act) a = anew;
    lgv = lgn;
  }
  float m2 = a;
  for (int off = 8; off; off >>= 1) m2 = fmaxf(m2, __shfl_xor(m2, off, 16));
  float ea2 = act ? __expf(a - m2) : 0.f;
  float ssum = ea2;
  for (int off = 8; off; off >>= 1) ssum += __shfl_xor(ssum, off, 16);
  float logZ = m2 + __logf(ssum);
  if (lane == 0) out_ll[b] = sc - logZ;
}

extern "C" void kernel_launch(void* const* d_in, const int* in_sizes, int n_in,
                              void* d_out, int out_size, void* d_ws, size_t ws_size,
                              hipStream_t stream) {
  const int* text = (const int*)d_in[0];
  const int* labels = (const int*)d_in[1];
  const float* emb = (const float*)d_in[2];
  const float* Wf = (const float*)d_in[3];
  const float* Uf = (const float*)d_in[4];
  const float* bf_ = (const float*)d_in[5];
  const float* Wb = (const float*)d_in[6];
  const float* Ub = (const float*)d_in[7];
  const float* bb_ = (const float*)d_in[8];
  const float* Wd = (const float*)d_in[9];
  const float* bd = (const float*)d_in[10];
  const float* trans = (const float*)d_in[11];
  (void)in_sizes; (void)n_in; (void)out_size; (void)ws_size;

  float* out = (float*)d_out;
  float* out_logits = out;                       // [BT*K]
  float* out_lens = out + (size_t)BT * Kn;       // [B]
  float* out_ll = out_lens + Bn;                 // [B]

  char* ws = (char*)d_ws;
  size_t o = 0;
  int* lens_i = (int*)(ws + o);                o += 1024;
  unsigned short* wt = (unsigned short*)(ws + o);  o += (size_t)2 * G4 * 128 * 2;
  unsigned short* ut = (unsigned short*)(ws + o);  o += (size_t)2 * G4 * 128 * 2;
  unsigned short* xw_s = (unsigned short*)(ws + o); o += (size_t)2 * BT * G4 * 2;  // [dir][t][bg][tid][4]
  unsigned short* hfb = (unsigned short*)(ws + o); o += (size_t)BT * Hn * 2;       // [t][b][128]
  unsigned short* hbb = (unsigned short*)(ws + o); o += (size_t)BT * Hn * 2;
  unsigned short* xwf = xw_s;
  unsigned short* xwb = xw_s + (size_t)BT * G4;

  hipLaunchKernelGGL(k_prep, dim3(1088), dim3(256), 0, stream,
                     text, Wf, Wb, Uf, Ub, wt, ut, lens_i, out_lens);
  hipLaunchKernelGGL(k_gemm_xw, dim3(1600), dim3(512), 0, stream,
                     text, emb, wt, bf_, bb_, xwf, xwb);
  hipLaunchKernelGGL(k_scan, dim3(128), dim3(512), 0, stream, ut, xw_s, hfb, hbb);
  hipLaunchKernelGGL(k_logits, dim3(400), dim3(128), 0, stream, hfb, hbb, Wd, bd, out_logits);
  hipLaunchKernelGGL(k_crf, dim3(Bn), dim3(64), 0, stream, out_logits, labels, lens_i, trans, out_ll);
}